// Round 5
// baseline (256.868 us; speedup 1.0000x reference)
//
#include <hip/hip_runtime.h>
#include <hip/hip_bf16.h>

#define NROWS 2048
#define CCH   64
#define FDIM  256
#define CF    16384   // C*F
#define EPSV  1e-3f

typedef __attribute__((ext_vector_type(8))) short  short8;
typedef __attribute__((ext_vector_type(4))) float  f32x4;

__device__ __forceinline__ ushort f2bf(float f) {
  union { float f; unsigned u; } v; v.f = f;
  unsigned r = v.u + 0x7fffu + ((v.u >> 16) & 1u);
  return (ushort)(r >> 16);
}
__device__ __forceinline__ float bf_lo(unsigned u) {
  union { unsigned u; float f; } v; v.u = u << 16; return v.f;
}
__device__ __forceinline__ float bf_hi(unsigned u) {
  union { unsigned u; float f; } v; v.u = u & 0xffff0000u; return v.f;
}
__device__ __forceinline__ unsigned pk2(float a, float b) {
  __hip_bfloat162 h = __float22bfloat162_rn(float2{a, b});
  union { __hip_bfloat162 h; unsigned u; } cv; cv.h = h; return cv.u;
}
__device__ __forceinline__ void gll16(const void* g, void* l) {
  __builtin_amdgcn_global_load_lds(
      (const __attribute__((address_space(1))) unsigned*)g,
      (__attribute__((address_space(3))) unsigned*)l, 16, 0, 0);
}

// ---------------- BN0 stats partials (no atomics) ----------------
// grid (16, 128), block 256. Each thread: 4 cols (float4) x 16 rows.
__global__ __launch_bounds__(256) void bn_stats_part(const float* __restrict__ src,
                                                     float* __restrict__ ps,
                                                     float* __restrict__ pq) {
  int cb = blockIdx.x * 256 + threadIdx.x;       // float4 col index 0..4095
  int by = blockIdx.y;
  const float4* p = (const float4*)src + (size_t)(by * 16) * (CF / 4) + cb;
  float s0 = 0, s1 = 0, s2 = 0, s3 = 0, q0 = 0, q1 = 0, q2 = 0, q3 = 0;
#pragma unroll
  for (int i = 0; i < 16; ++i) {
    float4 v = p[(size_t)i * (CF / 4)];
    s0 += v.x; q0 += v.x * v.x;
    s1 += v.y; q1 += v.y * v.y;
    s2 += v.z; q2 += v.z * v.z;
    s3 += v.w; q3 += v.w * v.w;
  }
  float4 sv; sv.x = s0; sv.y = s1; sv.z = s2; sv.w = s3;
  float4 qv; qv.x = q0; qv.y = q1; qv.z = q2; qv.w = q3;
  ((float4*)(ps + (size_t)by * CF))[cb] = sv;
  ((float4*)(pq + (size_t)by * CF))[cb] = qv;
}

// reduce nparts partials -> scale/shift. grid 64 x 256.
__global__ __launch_bounds__(256) void bn_finalize(const float* __restrict__ ps,
                                                   const float* __restrict__ pq,
                                                   int nparts,
                                                   const float* __restrict__ g,
                                                   const float* __restrict__ be,
                                                   float* __restrict__ scale,
                                                   float* __restrict__ shift) {
  int i = blockIdx.x * 256 + threadIdx.x;
  float s = 0, q = 0;
  for (int j = 0; j < nparts; ++j) {
    s += ps[(size_t)j * CF + i];
    q += pq[(size_t)j * CF + i];
  }
  float mean = s * (1.0f / NROWS);
  float var  = q * (1.0f / NROWS) - mean * mean;
  float sc   = g[i] * rsqrtf(var + EPSV);
  scale[i] = sc;
  shift[i] = be[i] - mean * sc;
}

// ---------------- weight f32 -> bf16 ----------------
__global__ __launch_bounds__(256) void cvt_f32_bf16(const float* __restrict__ w,
                                                    ushort* __restrict__ o, int n4) {
  size_t stride = (size_t)gridDim.x * blockDim.x;
  for (size_t i = (size_t)blockIdx.x * 256 + threadIdx.x; i < (size_t)n4; i += stride) {
    float4 v = ((const float4*)w)[i];
    ushort4 u;
    u.x = f2bf(v.x); u.y = f2bf(v.y); u.z = f2bf(v.z); u.w = f2bf(v.w);
    ((ushort4*)o)[i] = u;
  }
}

// ---------------- fused batched channel GEMM ----------------
// Tile: BM=128 rows x BN=64 out-cols x K=256. Grid 4096 = 16bm x 4bn x 64c.
// 4 waves, each 32 rows x 64 cols: m=2, n=4 frags, 64 MFMAs/wave.
// W-tile [64][256] bf16 = 32KB LDS, staged as two 16KB k-halves via
// global_load_lds (linear dest, XOR-swizzled source + reads).
// MODE 0: A = relu(x*scale+shift) from f32; epi: ybf=bf16(acc+bias) + BN1 partials.
// MODE 1: A = relu(ybf*scale+shift) from bf16; epi: out = xres + acc + bias.
template <int MODE>
__global__ __launch_bounds__(256, 4) void gemm_fused(const void* __restrict__ Asrc,
                                                     const ushort* __restrict__ W,
                                                     const float* __restrict__ bias,
                                                     const float* __restrict__ scale,
                                                     const float* __restrict__ shift,
                                                     const float* __restrict__ xres,
                                                     ushort* __restrict__ Ybf,
                                                     float* __restrict__ outf,
                                                     float* __restrict__ ps1,
                                                     float* __restrict__ pq1) {
  __shared__ __align__(16) ushort Ws[2][64 * 128];    // [k-half][row*128+k], 32KB
  __shared__ float scl[256], shf[256];                // 2KB
  __shared__ float sstat[2][4][4][16];                // 2KB (MODE0)

  const int t = threadIdx.x;
  const int lane = t & 63, wid = t >> 6;
  const int lm = lane & 15, lg = lane >> 4;

  // chunked bijective XCD swizzle (4096 = 8 x 512): XCD j gets 8 whole c-slices
  const int h  = blockIdx.x;
  const int wg = ((h & 7) << 9) | (h >> 3);
  const int bm = wg & 15, bn = (wg >> 4) & 3, c = wg >> 6;

  scl[t] = scale[c * FDIM + t];
  shf[t] = shift[c * FDIM + t];

  // W staging: per half 16KB = 256thr x 4 chunks x 16B, linear LDS dest.
  const int srow = t >> 4;            // 0..15
  const int sb   = (t & 15) * 16;     // 0..240 byte-in-half-row
  const int gsb  = sb ^ ((srow & 7) << 4);
  const char* Wrow = (const char*)(W + ((size_t)c * FDIM + bn * 64) * FDIM);
  char* Ws0 = (char*)&Ws[0][0];
  char* Ws1 = (char*)&Ws[1][0];

#pragma unroll
  for (int i = 0; i < 4; ++i) {
    const int row = i * 16 + srow;
    gll16(Wrow + (size_t)row * 512 + gsb, Ws0 + row * 256 + sb);
  }

  float bregs[4];
#pragma unroll
  for (int n = 0; n < 4; ++n)
    bregs[n] = bias[c * FDIM + bn * 64 + n * 16 + lm];

  const float*  AbF[2];
  const ushort* AbU[2];
#pragma unroll
  for (int m = 0; m < 2; ++m) {
    const size_t rowoff = (size_t)(bm * 128 + wid * 32 + m * 16 + lm) * CF + c * FDIM + lg * 8;
    AbF[m] = (const float*)Asrc + rowoff;
    AbU[m] = (const ushort*)Asrc + rowoff;
  }

  f32x4 acc[2][4];
#pragma unroll
  for (int m = 0; m < 2; ++m)
#pragma unroll
    for (int n = 0; n < 4; ++n) acc[m][n] = (f32x4){0.f, 0.f, 0.f, 0.f};

  __syncthreads();   // half-0 + scl/shf ready

  // issue half-1 staging; latency hides under ks=0..3
#pragma unroll
  for (int i = 0; i < 4; ++i) {
    const int row = i * 16 + srow;
    gll16(Wrow + (size_t)row * 512 + 256 + gsb, Ws1 + row * 256 + sb);
  }

#define KS_BODY(ksg, WsH, ksl)                                                   \
  {                                                                              \
    float4 sc0 = *(const float4*)&scl[(ksg) * 32 + lg * 8];                      \
    float4 sc1 = *(const float4*)&scl[(ksg) * 32 + lg * 8 + 4];                  \
    float4 sh0 = *(const float4*)&shf[(ksg) * 32 + lg * 8];                      \
    float4 sh1 = *(const float4*)&shf[(ksg) * 32 + lg * 8 + 4];                  \
    short8 af[2];                                                                \
    _Pragma("unroll")                                                            \
    for (int m = 0; m < 2; ++m) {                                                \
      float v0, v1, v2, v3, v4, v5, v6, v7;                                      \
      if (MODE == 0) {                                                           \
        float4 a0 = *(const float4*)(AbF[m] + (ksg) * 32);                       \
        float4 a1 = *(const float4*)(AbF[m] + (ksg) * 32 + 4);                   \
        v0 = a0.x; v1 = a0.y; v2 = a0.z; v3 = a0.w;                              \
        v4 = a1.x; v5 = a1.y; v6 = a1.z; v7 = a1.w;                              \
      } else {                                                                   \
        uint4 u = *(const uint4*)(AbU[m] + (ksg) * 32);                          \
        v0 = bf_lo(u.x); v1 = bf_hi(u.x); v2 = bf_lo(u.y); v3 = bf_hi(u.y);      \
        v4 = bf_lo(u.z); v5 = bf_hi(u.z); v6 = bf_lo(u.w); v7 = bf_hi(u.w);      \
      }                                                                          \
      v0 = fmaxf(fmaf(v0, sc0.x, sh0.x), 0.f);                                   \
      v1 = fmaxf(fmaf(v1, sc0.y, sh0.y), 0.f);                                   \
      v2 = fmaxf(fmaf(v2, sc0.z, sh0.z), 0.f);                                   \
      v3 = fmaxf(fmaf(v3, sc0.w, sh0.w), 0.f);                                   \
      v4 = fmaxf(fmaf(v4, sc1.x, sh1.x), 0.f);                                   \
      v5 = fmaxf(fmaf(v5, sc1.y, sh1.y), 0.f);                                   \
      v6 = fmaxf(fmaf(v6, sc1.z, sh1.z), 0.f);                                   \
      v7 = fmaxf(fmaf(v7, sc1.w, sh1.w), 0.f);                                   \
      union { short8 s; unsigned u[4]; } pkd;                                    \
      pkd.u[0] = pk2(v0, v1); pkd.u[1] = pk2(v2, v3);                            \
      pkd.u[2] = pk2(v4, v5); pkd.u[3] = pk2(v6, v7);                            \
      af[m] = pkd.s;                                                             \
    }                                                                            \
    short8 bv[4];                                                                \
    _Pragma("unroll")                                                            \
    for (int n = 0; n < 4; ++n) {                                                \
      const int ro = n * 16 + lm;                                                \
      const int byt = ((ksl) * 64 + lg * 16) ^ ((ro & 7) << 4);                  \
      bv[n] = *(const short8*)((WsH) + ro * 256 + byt);                          \
    }                                                                            \
    _Pragma("unroll")                                                            \
    for (int m = 0; m < 2; ++m)                                                  \
      _Pragma("unroll")                                                          \
      for (int n = 0; n < 4; ++n)                                                \
        acc[m][n] = __builtin_amdgcn_mfma_f32_16x16x32_bf16(af[m], bv[n],        \
                                                            acc[m][n], 0, 0, 0); \
  }

#pragma unroll
  for (int ks = 0; ks < 4; ++ks) KS_BODY(ks, Ws0, ks)
  __syncthreads();   // half-1 staged
#pragma unroll
  for (int ks = 4; ks < 8; ++ks) KS_BODY(ks, Ws1, ks - 4)

  if (MODE == 0) {
    // ---- BN1 column partial stats from f32 acc ----
#pragma unroll
    for (int n = 0; n < 4; ++n) {
      float ss = 0, qq = 0;
#pragma unroll
      for (int m = 0; m < 2; ++m)
#pragma unroll
        for (int j = 0; j < 4; ++j) {
          float v = acc[m][n][j] + bregs[n];
          ss += v; qq += v * v;
        }
      ss += __shfl_xor(ss, 16); ss += __shfl_xor(ss, 32);
      qq += __shfl_xor(qq, 16); qq += __shfl_xor(qq, 32);
      if (lg == 0) {
        sstat[0][wid][n][lm] = ss;
        sstat[1][wid][n][lm] = qq;
      }
    }
    __syncthreads();   // MFMA ds-reads done + sstat written; Ws reusable

    // ---- C -> LDS f32 [128][64], swz col^(((row>>2)&3)<<4) = 2-way max ----
    float* Cs = (float*)&Ws[0][0];   // 32KB
#pragma unroll
    for (int m = 0; m < 2; ++m) {
      const int rbase = wid * 32 + m * 16 + lg * 4;
      const int xd = ((rbase >> 2) & 3) << 4;     // == per-lg window
#pragma unroll
      for (int n = 0; n < 4; ++n) {
        const int col = n * 16 + lm;
#pragma unroll
        for (int j = 0; j < 4; ++j)
          Cs[(rbase + j) * 64 + (col ^ xd)] = acc[m][n][j] + bregs[n];
      }
    }
    __syncthreads();

    // ---- coalesced bf16 writeout: 8 thr/row x 32 rows/pass x 4 passes ----
    const int rt = t >> 3;           // 0..31
    const int pcol = (t & 7) * 8;    // 0..56
#pragma unroll
    for (int rb = 0; rb < 4; ++rb) {
      const int row = rb * 32 + rt;
      const int xd = ((row >> 2) & 3) << 4;
      f32x4 v0 = *(const f32x4*)&Cs[row * 64 + (pcol ^ xd)];
      f32x4 v1 = *(const f32x4*)&Cs[row * 64 + ((pcol + 4) ^ xd)];
      uint4 u;
      u.x = pk2(v0[0], v0[1]); u.y = pk2(v0[2], v0[3]);
      u.z = pk2(v1[0], v1[1]); u.w = pk2(v1[2], v1[3]);
      *(uint4*)(Ybf + (size_t)(bm * 128 + row) * CF + c * FDIM + bn * 64 + pcol) = u;
    }

    // ---- partial stats writeout: 128 threads = 2 stats x 4n x 16 cols ----
    if (t < 128) {
      const int stat = t >> 6;
      const int n = (t >> 4) & 3, lmm = t & 15;
      float v = sstat[stat][0][n][lmm] + sstat[stat][1][n][lmm] +
                sstat[stat][2][n][lmm] + sstat[stat][3][n][lmm];
      float* dst = stat ? pq1 : ps1;
      dst[(size_t)bm * CF + c * FDIM + bn * 64 + n * 16 + lmm] = v;
    }
  } else {
    // ---- MODE 1: direct f32 stores (64B runs per 16 lanes) ----
#pragma unroll
    for (int n = 0; n < 4; ++n) {
      const int col = c * FDIM + bn * 64 + n * 16 + lm;
      const float bb = bregs[n];
#pragma unroll
      for (int m = 0; m < 2; ++m) {
        const int r0 = bm * 128 + wid * 32 + m * 16 + lg * 4;
#pragma unroll
        for (int j = 0; j < 4; ++j) {
          const size_t gofs = (size_t)(r0 + j) * CF + col;
          outf[gofs] = xres[gofs] + acc[m][n][j] + bb;
        }
      }
    }
  }
}

// ---------------- launch ----------------
extern "C" void kernel_launch(void* const* d_in, const int* in_sizes, int n_in,
                              void* d_out, int out_size, void* d_ws, size_t ws_size,
                              hipStream_t stream) {
  const float* x   = (const float*)d_in[0];
  const float* w0  = (const float*)d_in[1];
  const float* b0  = (const float*)d_in[2];
  const float* w1  = (const float*)d_in[3];
  const float* b1  = (const float*)d_in[4];
  const float* g0  = (const float*)d_in[5];
  const float* be0 = (const float*)d_in[6];
  const float* g1  = (const float*)d_in[7];
  const float* be1 = (const float*)d_in[8];
  float* out = (float*)d_out;

  char* ws = (char*)d_ws;
  float* ps0    = (float*)ws;                         // 128*CF
  float* pq0    = ps0 + (size_t)128 * CF;             // 128*CF
  float* ps1    = pq0 + (size_t)128 * CF;             // 16*CF
  float* pq1    = ps1 + (size_t)16 * CF;              // 16*CF
  float* scale0 = pq1 + (size_t)16 * CF;
  float* shift0 = scale0 + CF;
  float* scale1 = shift0 + CF;
  float* shift1 = scale1 + CF;
  ushort* w0bf = (ushort*)(shift1 + CF);
  ushort* w1bf = w0bf + (size_t)CCH * FDIM * FDIM;
  ushort* ybf  = w1bf + (size_t)CCH * FDIM * FDIM;

  const int NW4 = CCH * FDIM * FDIM / 4;
  cvt_f32_bf16<<<2048, 256, 0, stream>>>(w0, w0bf, NW4);
  cvt_f32_bf16<<<2048, 256, 0, stream>>>(w1, w1bf, NW4);

  // BN0 stats over x (no atomics)
  bn_stats_part<<<dim3(16, 128), 256, 0, stream>>>(x, ps0, pq0);
  bn_finalize<<<64, 256, 0, stream>>>(ps0, pq0, 128, g0, be0, scale0, shift0);

  // linear0 fused: A=relu(bn0(x)), out ybf + BN1 partials
  gemm_fused<0><<<4096, 256, 0, stream>>>(
      x, w0bf, b0, scale0, shift0, nullptr, ybf, nullptr, ps1, pq1);

  bn_finalize<<<64, 256, 0, stream>>>(ps1, pq1, 16, g1, be1, scale1, shift1);

  // linear1 fused: A=relu(bn1(ybf)), out = x + acc + b1
  gemm_fused<1><<<4096, 256, 0, stream>>>(
      ybf, w1bf, b1, scale1, shift1, x, nullptr, out, nullptr, nullptr);
}

// Round 6
// 206.456 us; speedup vs baseline: 1.2442x; 1.2442x over previous
//
#include <hip/hip_runtime.h>
#include <hip/hip_bf16.h>

#define NROWS 2048
#define CCH   64
#define FDIM  256
#define CF    16384   // C*F
#define EPSV  1e-3f

typedef __attribute__((ext_vector_type(8))) short  short8;
typedef __attribute__((ext_vector_type(4))) float  f32x4;

__device__ __forceinline__ ushort f2bf(float f) {
  union { float f; unsigned u; } v; v.f = f;
  unsigned r = v.u + 0x7fffu + ((v.u >> 16) & 1u);
  return (ushort)(r >> 16);
}
__device__ __forceinline__ float bf_lo(unsigned u) {
  union { unsigned u; float f; } v; v.u = u << 16; return v.f;
}
__device__ __forceinline__ float bf_hi(unsigned u) {
  union { unsigned u; float f; } v; v.u = u & 0xffff0000u; return v.f;
}
__device__ __forceinline__ unsigned pk2(float a, float b) {
  __hip_bfloat162 h = __float22bfloat162_rn(float2{a, b});
  union { __hip_bfloat162 h; unsigned u; } cv; cv.h = h; return cv.u;
}
__device__ __forceinline__ void gll16(const void* g, void* l) {
  __builtin_amdgcn_global_load_lds(
      (const __attribute__((address_space(1))) unsigned*)g,
      (__attribute__((address_space(3))) unsigned*)l, 16, 0, 0);
}

// ---------------- BN0 stats partials (no atomics) ----------------
// grid (16, 128), block 256. Each thread: 4 cols (float4) x 16 rows.
__global__ __launch_bounds__(256) void bn_stats_part(const float* __restrict__ src,
                                                     float* __restrict__ ps,
                                                     float* __restrict__ pq) {
  int cb = blockIdx.x * 256 + threadIdx.x;       // float4 col index 0..4095
  int by = blockIdx.y;
  const float4* p = (const float4*)src + (size_t)(by * 16) * (CF / 4) + cb;
  float s0 = 0, s1 = 0, s2 = 0, s3 = 0, q0 = 0, q1 = 0, q2 = 0, q3 = 0;
#pragma unroll
  for (int i = 0; i < 16; ++i) {
    float4 v = p[(size_t)i * (CF / 4)];
    s0 += v.x; q0 += v.x * v.x;
    s1 += v.y; q1 += v.y * v.y;
    s2 += v.z; q2 += v.z * v.z;
    s3 += v.w; q3 += v.w * v.w;
  }
  float4 sv; sv.x = s0; sv.y = s1; sv.z = s2; sv.w = s3;
  float4 qv; qv.x = q0; qv.y = q1; qv.z = q2; qv.w = q3;
  ((float4*)(ps + (size_t)by * CF))[cb] = sv;
  ((float4*)(pq + (size_t)by * CF))[cb] = qv;
}

// reduce nparts partials -> scale/shift. grid 64 x 256.
__global__ __launch_bounds__(256) void bn_finalize(const float* __restrict__ ps,
                                                   const float* __restrict__ pq,
                                                   int nparts,
                                                   const float* __restrict__ g,
                                                   const float* __restrict__ be,
                                                   float* __restrict__ scale,
                                                   float* __restrict__ shift) {
  int i = blockIdx.x * 256 + threadIdx.x;
  float s = 0, q = 0;
  for (int j = 0; j < nparts; ++j) {
    s += ps[(size_t)j * CF + i];
    q += pq[(size_t)j * CF + i];
  }
  float mean = s * (1.0f / NROWS);
  float var  = q * (1.0f / NROWS) - mean * mean;
  float sc   = g[i] * rsqrtf(var + EPSV);
  scale[i] = sc;
  shift[i] = be[i] - mean * sc;
}

// ---------------- both weights f32 -> bf16, one launch ----------------
__global__ __launch_bounds__(256) void cvt2_f32_bf16(const float* __restrict__ w0,
                                                     const float* __restrict__ w1,
                                                     ushort* __restrict__ o0,
                                                     ushort* __restrict__ o1, int n4) {
  size_t stride = (size_t)gridDim.x * blockDim.x;
  for (size_t i = (size_t)blockIdx.x * 256 + threadIdx.x; i < (size_t)(2 * n4); i += stride) {
    const float* src = (i < (size_t)n4) ? w0 : w1;
    ushort* dst = (i < (size_t)n4) ? o0 : o1;
    size_t j = (i < (size_t)n4) ? i : i - n4;
    float4 v = ((const float4*)src)[j];
    ushort4 u;
    u.x = f2bf(v.x); u.y = f2bf(v.y); u.z = f2bf(v.z); u.w = f2bf(v.w);
    ((ushort4*)dst)[j] = u;
  }
}

// ---------------- fused batched channel GEMM ----------------
// Tile: BM=128 x BN=128 x K=256. Grid 2048 = 16bm x 2bn x 64c. 4 waves,
// each 32 rows x 128 cols (m=2, n=8 frags). W [128][256] bf16 staged as two
// 32KB k-halves via global_load_lds (linear dest, XOR-swizzled src+reads).
// A operand: global -> 4-slot register ring (depth-4 prefetch), BN+ReLU+pack
// applied at use. MODE 0: A from f32 x; epi: ybf + BN1 partials.
// MODE 1: A from bf16 ybf; epi: out = xres + acc + bias.
template <int MODE>
__global__ __launch_bounds__(256, 2) void gemm_fused(const void* __restrict__ Asrc,
                                                     const ushort* __restrict__ W,
                                                     const float* __restrict__ bias,
                                                     const float* __restrict__ scale,
                                                     const float* __restrict__ shift,
                                                     const float* __restrict__ xres,
                                                     ushort* __restrict__ Ybf,
                                                     float* __restrict__ outf,
                                                     float* __restrict__ ps1,
                                                     float* __restrict__ pq1) {
  __shared__ __align__(16) ushort Ws[2][128 * 128];   // 64KB; reused as Cs f32[128][128]
  __shared__ float scl[256], shf[256];                // 2KB
  __shared__ float sstat[2][4][8][16];                // 4KB (MODE0)

  const int t = threadIdx.x;
  const int lane = t & 63, wid = t >> 6;
  const int lm = lane & 15, lg = lane >> 4;

  // bijective XCD swizzle (nwg=2048): XCD j gets wg in [j*256,(j+1)*256)
  const int h  = blockIdx.x;
  const int wg = ((h & 7) << 8) | (h >> 3);
  const int bm = wg & 15, bn = (wg >> 4) & 1, c = wg >> 5;

  scl[t] = scale[c * FDIM + t];
  shf[t] = shift[c * FDIM + t];

  // W staging: per half 32KB = 256thr x 8 chunks x 16B, linear LDS dest.
  const int srow = t >> 4;            // 0..15
  const int sb   = (t & 15) * 16;     // 0..240 byte-in-half-row
  const int gsb  = sb ^ ((srow & 7) << 4);
  const char* Wrow = (const char*)(W + ((size_t)c * FDIM + bn * 128) * FDIM);
  char* Ws0 = (char*)&Ws[0][0];
  char* Ws1 = (char*)&Ws[1][0];

#pragma unroll
  for (int i = 0; i < 8; ++i) {
    const int row = i * 16 + srow;
    gll16(Wrow + (size_t)row * 512 + gsb, Ws0 + row * 256 + sb);
  }

  float bregs[8];
#pragma unroll
  for (int n = 0; n < 8; ++n)
    bregs[n] = bias[c * FDIM + bn * 128 + n * 16 + lm];

  const float*  AbF[2];
  const ushort* AbU[2];
#pragma unroll
  for (int m = 0; m < 2; ++m) {
    const size_t rowoff = (size_t)(bm * 128 + wid * 32 + m * 16 + lm) * CF + c * FDIM + lg * 8;
    AbF[m] = (const float*)Asrc + rowoff;
    AbU[m] = (const ushort*)Asrc + rowoff;
  }

  // ---- A raw register ring, depth 4 (all indices compile-time) ----
  float4 ra0[4][2], ra1[4][2];   // MODE 0
  uint4  ru[4][2];               // MODE 1

#define PRELOAD(slot, ksg)                                                \
  _Pragma("unroll")                                                       \
  for (int m = 0; m < 2; ++m) {                                           \
    if (MODE == 0) {                                                      \
      ra0[slot][m] = *(const float4*)(AbF[m] + (ksg) * 32);               \
      ra1[slot][m] = *(const float4*)(AbF[m] + (ksg) * 32 + 4);           \
    } else {                                                              \
      ru[slot][m] = *(const uint4*)(AbU[m] + (ksg) * 32);                 \
    }                                                                     \
  }

#pragma unroll
  for (int p = 0; p < 4; ++p) PRELOAD(p, p)

  f32x4 acc[2][8];
#pragma unroll
  for (int m = 0; m < 2; ++m)
#pragma unroll
    for (int n = 0; n < 8; ++n) acc[m][n] = (f32x4){0.f, 0.f, 0.f, 0.f};

  __syncthreads();   // half-0 + scl/shf ready

  // issue half-1 staging; latency hides under ks=0..3
#pragma unroll
  for (int i = 0; i < 8; ++i) {
    const int row = i * 16 + srow;
    gll16(Wrow + (size_t)row * 512 + 256 + gsb, Ws1 + row * 256 + sb);
  }

#define KS_BODY(ksg, WsH, ksl)                                                   \
  {                                                                              \
    const int slot = (ksg) & 3;                                                  \
    float4 sc0 = *(const float4*)&scl[(ksg) * 32 + lg * 8];                      \
    float4 sc1 = *(const float4*)&scl[(ksg) * 32 + lg * 8 + 4];                  \
    float4 sh0 = *(const float4*)&shf[(ksg) * 32 + lg * 8];                      \
    float4 sh1 = *(const float4*)&shf[(ksg) * 32 + lg * 8 + 4];                  \
    short8 af[2];                                                                \
    _Pragma("unroll")                                                            \
    for (int m = 0; m < 2; ++m) {                                                \
      float v0, v1, v2, v3, v4, v5, v6, v7;                                      \
      if (MODE == 0) {                                                           \
        float4 a0 = ra0[slot][m];                                                \
        float4 a1 = ra1[slot][m];                                                \
        v0 = a0.x; v1 = a0.y; v2 = a0.z; v3 = a0.w;                              \
        v4 = a1.x; v5 = a1.y; v6 = a1.z; v7 = a1.w;                              \
      } else {                                                                   \
        uint4 u = ru[slot][m];                                                   \
        v0 = bf_lo(u.x); v1 = bf_hi(u.x); v2 = bf_lo(u.y); v3 = bf_hi(u.y);      \
        v4 = bf_lo(u.z); v5 = bf_hi(u.z); v6 = bf_lo(u.w); v7 = bf_hi(u.w);      \
      }                                                                          \
      v0 = fmaxf(fmaf(v0, sc0.x, sh0.x), 0.f);                                   \
      v1 = fmaxf(fmaf(v1, sc0.y, sh0.y), 0.f);                                   \
      v2 = fmaxf(fmaf(v2, sc0.z, sh0.z), 0.f);                                   \
      v3 = fmaxf(fmaf(v3, sc0.w, sh0.w), 0.f);                                   \
      v4 = fmaxf(fmaf(v4, sc1.x, sh1.x), 0.f);                                   \
      v5 = fmaxf(fmaf(v5, sc1.y, sh1.y), 0.f);                                   \
      v6 = fmaxf(fmaf(v6, sc1.z, sh1.z), 0.f);                                   \
      v7 = fmaxf(fmaf(v7, sc1.w, sh1.w), 0.f);                                   \
      union { short8 s; unsigned u[4]; } pkd;                                    \
      pkd.u[0] = pk2(v0, v1); pkd.u[1] = pk2(v2, v3);                            \
      pkd.u[2] = pk2(v4, v5); pkd.u[3] = pk2(v6, v7);                            \
      af[m] = pkd.s;                                                             \
    }                                                                            \
    if ((ksg) < 4) PRELOAD(slot, (ksg) + 4)                                      \
    short8 bv[8];                                                                \
    _Pragma("unroll")                                                            \
    for (int n = 0; n < 8; ++n) {                                                \
      const int ro = n * 16 + lm;                                                \
      const int byt = ((ksl) * 64 + lg * 16) ^ ((ro & 7) << 4);                  \
      bv[n] = *(const short8*)((WsH) + ro * 256 + byt);                          \
    }                                                                            \
    _Pragma("unroll")                                                            \
    for (int m = 0; m < 2; ++m)                                                  \
      _Pragma("unroll")                                                          \
      for (int n = 0; n < 8; ++n)                                                \
        acc[m][n] = __builtin_amdgcn_mfma_f32_16x16x32_bf16(af[m], bv[n],        \
                                                            acc[m][n], 0, 0, 0); \
  }

#pragma unroll
  for (int ks = 0; ks < 4; ++ks) KS_BODY(ks, Ws0, ks)
  __syncthreads();   // half-1 staged
#pragma unroll
  for (int ks = 4; ks < 8; ++ks) KS_BODY(ks, Ws1, ks - 4)

  if (MODE == 0) {
    // ---- BN1 column partial stats from f32 acc ----
#pragma unroll
    for (int n = 0; n < 8; ++n) {
      float ss = 0, qq = 0;
#pragma unroll
      for (int m = 0; m < 2; ++m)
#pragma unroll
        for (int j = 0; j < 4; ++j) {
          float v = acc[m][n][j] + bregs[n];
          ss += v; qq += v * v;
        }
      ss += __shfl_xor(ss, 16); ss += __shfl_xor(ss, 32);
      qq += __shfl_xor(qq, 16); qq += __shfl_xor(qq, 32);
      if (lg == 0) {
        sstat[0][wid][n][lm] = ss;
        sstat[1][wid][n][lm] = qq;
      }
    }
  }
  __syncthreads();   // all Ws reads done + sstat written; Ws reusable as Cs

  // ---- C -> LDS f32 [128][128], swz col^(((row>>2)&3)<<4) -> 2-way max ----
  float* Cs = (float*)&Ws[0][0];   // 64KB
#pragma unroll
  for (int m = 0; m < 2; ++m) {
    const int rbase = wid * 32 + m * 16 + lg * 4;
    const int xd = lg << 4;        // == ((rbase>>2)&3)<<4
#pragma unroll
    for (int n = 0; n < 8; ++n) {
      const int col = n * 16 + lm;
#pragma unroll
      for (int j = 0; j < 4; ++j)
        Cs[(rbase + j) * 128 + (col ^ xd)] = acc[m][n][j] + bregs[n];
    }
  }
  __syncthreads();

  // ---- coalesced writeout: 16 thr/row, 16 rows/pass, 8 passes ----
  const int prow = t >> 4;          // 0..15
  const int pcol = (t & 15) * 8;    // 0..120
#pragma unroll
  for (int rb = 0; rb < 8; ++rb) {
    const int row = rb * 16 + prow;
    const int xd = ((row >> 2) & 3) << 4;
    f32x4 v0 = *(const f32x4*)&Cs[row * 128 + (pcol ^ xd)];
    f32x4 v1 = *(const f32x4*)&Cs[row * 128 + ((pcol + 4) ^ xd)];
    const size_t gofs = (size_t)(bm * 128 + row) * CF + c * FDIM + bn * 128 + pcol;
    if (MODE == 0) {
      uint4 u;
      u.x = pk2(v0[0], v0[1]); u.y = pk2(v0[2], v0[3]);
      u.z = pk2(v1[0], v1[1]); u.w = pk2(v1[2], v1[3]);
      *(uint4*)(Ybf + gofs) = u;
    } else {
      float4 x0 = *(const float4*)(xres + gofs);
      float4 x1 = *(const float4*)(xres + gofs + 4);
      float4 o0, o1;
      o0.x = x0.x + v0[0]; o0.y = x0.y + v0[1]; o0.z = x0.z + v0[2]; o0.w = x0.w + v0[3];
      o1.x = x1.x + v1[0]; o1.y = x1.y + v1[1]; o1.z = x1.z + v1[2]; o1.w = x1.w + v1[3];
      *(float4*)(outf + gofs) = o0;
      *(float4*)(outf + gofs + 4) = o1;
    }
  }

  if (MODE == 0) {
    // ---- partial stats writeout: 256 thr = 2 stats x 128 cols ----
    const int stat = t >> 7;
    const int idx = t & 127;
    const int n = idx >> 4, lmm = idx & 15;
    float v = sstat[stat][0][n][lmm] + sstat[stat][1][n][lmm] +
              sstat[stat][2][n][lmm] + sstat[stat][3][n][lmm];
    float* dst = stat ? pq1 : ps1;
    dst[(size_t)bm * CF + c * FDIM + bn * 128 + n * 16 + lmm] = v;
  }
}

// ---------------- launch ----------------
extern "C" void kernel_launch(void* const* d_in, const int* in_sizes, int n_in,
                              void* d_out, int out_size, void* d_ws, size_t ws_size,
                              hipStream_t stream) {
  const float* x   = (const float*)d_in[0];
  const float* w0  = (const float*)d_in[1];
  const float* b0  = (const float*)d_in[2];
  const float* w1  = (const float*)d_in[3];
  const float* b1  = (const float*)d_in[4];
  const float* g0  = (const float*)d_in[5];
  const float* be0 = (const float*)d_in[6];
  const float* g1  = (const float*)d_in[7];
  const float* be1 = (const float*)d_in[8];
  float* out = (float*)d_out;

  char* ws = (char*)d_ws;
  float* ps0    = (float*)ws;                         // 128*CF
  float* pq0    = ps0 + (size_t)128 * CF;             // 128*CF
  float* ps1    = pq0 + (size_t)128 * CF;             // 16*CF
  float* pq1    = ps1 + (size_t)16 * CF;              // 16*CF
  float* scale0 = pq1 + (size_t)16 * CF;
  float* shift0 = scale0 + CF;
  float* scale1 = shift0 + CF;
  float* shift1 = scale1 + CF;
  ushort* w0bf = (ushort*)(shift1 + CF);
  ushort* w1bf = w0bf + (size_t)CCH * FDIM * FDIM;
  ushort* ybf  = w1bf + (size_t)CCH * FDIM * FDIM;

  const int NW4 = CCH * FDIM * FDIM / 4;
  cvt2_f32_bf16<<<4096, 256, 0, stream>>>(w0, w1, w0bf, w1bf, NW4);

  // BN0 stats over x (no atomics)
  bn_stats_part<<<dim3(16, 128), 256, 0, stream>>>(x, ps0, pq0);
  bn_finalize<<<64, 256, 0, stream>>>(ps0, pq0, 128, g0, be0, scale0, shift0);

  // linear0 fused: A=relu(bn0(x)), out ybf + BN1 partials
  gemm_fused<0><<<2048, 256, 0, stream>>>(
      x, w0bf, b0, scale0, shift0, nullptr, ybf, nullptr, ps1, pq1);

  bn_finalize<<<64, 256, 0, stream>>>(ps1, pq1, 16, g1, be1, scale1, shift1);

  // linear1 fused: A=relu(bn1(ybf)), out = x + acc + b1
  gemm_fused<1><<<2048, 256, 0, stream>>>(
      ybf, w1bf, b1, scale1, shift1, x, nullptr, out, nullptr, nullptr);
}